// Round 1
// baseline (449.805 us; speedup 1.0000x reference)
//
#include <hip/hip_runtime.h>
#include <math.h>

// Blocksparse softmax, causal block-tril layout.
// B=8, R=C=64, BS=64, n_blocks = 8 * 2080 = 16640.
// Block (b,r,c), c<=r lives at linear index b*2080 + r*(r+1)/2 + c.
// One workgroup (256 threads) per dense row (b, r, i): row has (r+1)*64
// active columns, held in registers (<=16 float4/thread) across all phases.

__global__ __launch_bounds__(256) void bs_softmax_kernel(
    const float* __restrict__ x, float* __restrict__ out) {
    const int bid = blockIdx.x;          // 0 .. 8*64*64-1
    const int i   = bid & 63;            // row within block
    const int r   = (bid >> 6) & 63;     // block row
    const int b   = bid >> 12;           // batch

    const long long base =
        ((long long)b * 2080 + (long long)(r * (r + 1) / 2)) * 4096 + (long long)i * 64;
    const int n    = (r + 1) * 64;       // active columns in this dense row
    const int nvec = n >> 2;             // float4 count

    const int t = threadIdx.x;

    float4 v[4];
    int cnt = 0;
    float m = -INFINITY;

    // Phase 1: load row into registers, thread-local max.
    for (int vi = t; vi < nvec; vi += 256) {
        const int col = vi << 2;
        const int cb  = col >> 6;        // which sparse block along the row
        const int j   = col & 63;        // column inside block
        float4 val = *(const float4*)(x + base + (long long)cb * 4096 + j);
        v[cnt++] = val;
        m = fmaxf(m, fmaxf(fmaxf(val.x, val.y), fmaxf(val.z, val.w)));
    }

    // Wave64 max reduce, then cross-wave via LDS.
    #pragma unroll
    for (int off = 32; off >= 1; off >>= 1)
        m = fmaxf(m, __shfl_xor(m, off, 64));
    __shared__ float sm[4];
    __shared__ float ss[4];
    const int wave = t >> 6;
    if ((t & 63) == 0) sm[wave] = m;
    __syncthreads();
    m = fmaxf(fmaxf(sm[0], sm[1]), fmaxf(sm[2], sm[3]));

    // Phase 2: exp in registers, thread-local sum.
    float s = 0.0f;
    for (int k = 0; k < cnt; ++k) {
        float4 val = v[k];
        val.x = __expf(val.x - m);
        val.y = __expf(val.y - m);
        val.z = __expf(val.z - m);
        val.w = __expf(val.w - m);
        v[k] = val;
        s += (val.x + val.y) + (val.z + val.w);
    }
    #pragma unroll
    for (int off = 32; off >= 1; off >>= 1)
        s += __shfl_xor(s, off, 64);
    if ((t & 63) == 0) ss[wave] = s;
    __syncthreads();
    s = (ss[0] + ss[1]) + (ss[2] + ss[3]);
    const float inv = 1.0f / s;

    // Phase 3: scale + store.
    int k = 0;
    for (int vi = t; vi < nvec; vi += 256) {
        const int col = vi << 2;
        const int cb  = col >> 6;
        const int j   = col & 63;
        float4 val = v[k++];
        val.x *= inv; val.y *= inv; val.z *= inv; val.w *= inv;
        *(float4*)(out + base + (long long)cb * 4096 + j) = val;
    }
}

extern "C" void kernel_launch(void* const* d_in, const int* in_sizes, int n_in,
                              void* d_out, int out_size, void* d_ws, size_t ws_size,
                              hipStream_t stream) {
    const float* x = (const float*)d_in[0];
    float* out = (float*)d_out;
    // 8 batches * 64 block-rows * 64 rows-per-block = 32768 dense rows.
    dim3 grid(8 * 64 * 64);
    dim3 block(256);
    bs_softmax_kernel<<<grid, block, 0, stream>>>(x, out);
}

// Round 2
// 438.308 us; speedup vs baseline: 1.0262x; 1.0262x over previous
//
#include <hip/hip_runtime.h>
#include <math.h>

// Blocksparse softmax, causal block-tril layout.
// B=8, R=C=64, BS=64, n_blocks = 8 * 2080 = 16640.
// Block (b,r,c), c<=r lives at linear index b*2080 + r*(r+1)/2 + c.
// One workgroup (256 threads) per dense row (b, r, i): row has (r+1)*64
// active columns = (r+1)*16 float4 <= 1024, i.e. <= 4 float4/thread.
// v[4] uses ONLY compile-time indices so it stays in VGPRs (dynamic
// indexing would spill to scratch = global memory traffic).

__global__ __launch_bounds__(256) void bs_softmax_kernel(
    const float* __restrict__ x, float* __restrict__ out) {
    const int bid = blockIdx.x;          // 0 .. 8*64*64-1
    const int i   = bid & 63;            // row within block
    const int r   = 63 - ((bid >> 6) & 63); // block row, big rows dispatched first
    const int b   = bid >> 12;           // batch

    // All addressing fits in int: 16640*4096 = 68,157,440 < 2^31.
    const int base = (b * 2080 + ((r * (r + 1)) >> 1)) * 4096 + i * 64;
    const int nvec = (r + 1) << 4;       // float4 count in this dense row

    const int t = threadIdx.x;

    float4 v[4];
    float m = -INFINITY;

    // Phase 1: load row into registers (compile-time indexed), local max.
    #pragma unroll
    for (int k = 0; k < 4; ++k) {
        const int vi = t + (k << 8);
        if (vi < nvec) {
            const int col = vi << 2;
            const int cb  = col >> 6;        // sparse block along the row
            const int j   = col & 63;        // column inside block
            const float4 val = *(const float4*)(x + base + cb * 4096 + j);
            v[k] = val;
            m = fmaxf(m, fmaxf(fmaxf(val.x, val.y), fmaxf(val.z, val.w)));
        } else {
            v[k] = make_float4(-INFINITY, -INFINITY, -INFINITY, -INFINITY);
        }
    }

    // Wave64 max reduce, then cross-wave via LDS.
    #pragma unroll
    for (int off = 32; off >= 1; off >>= 1)
        m = fmaxf(m, __shfl_xor(m, off, 64));
    __shared__ float sm[4];
    __shared__ float ss[4];
    const int wave = t >> 6;
    if ((t & 63) == 0) sm[wave] = m;
    __syncthreads();
    m = fmaxf(fmaxf(sm[0], sm[1]), fmaxf(sm[2], sm[3]));

    // Phase 2: exp in registers, local sum. Inactive slots are -inf -> 0.
    float s = 0.0f;
    #pragma unroll
    for (int k = 0; k < 4; ++k) {
        float4 val = v[k];
        val.x = __expf(val.x - m);
        val.y = __expf(val.y - m);
        val.z = __expf(val.z - m);
        val.w = __expf(val.w - m);
        v[k] = val;
        s += (val.x + val.y) + (val.z + val.w);
    }
    #pragma unroll
    for (int off = 32; off >= 1; off >>= 1)
        s += __shfl_xor(s, off, 64);
    if ((t & 63) == 0) ss[wave] = s;
    __syncthreads();
    s = (ss[0] + ss[1]) + (ss[2] + ss[3]);
    const float inv = 1.0f / s;

    // Phase 3: scale + store (predicated, compile-time indexed).
    #pragma unroll
    for (int k = 0; k < 4; ++k) {
        const int vi = t + (k << 8);
        if (vi < nvec) {
            const int col = vi << 2;
            const int cb  = col >> 6;
            const int j   = col & 63;
            float4 val = v[k];
            val.x *= inv; val.y *= inv; val.z *= inv; val.w *= inv;
            *(float4*)(out + base + cb * 4096 + j) = val;
        }
    }
}

extern "C" void kernel_launch(void* const* d_in, const int* in_sizes, int n_in,
                              void* d_out, int out_size, void* d_ws, size_t ws_size,
                              hipStream_t stream) {
    const float* x = (const float*)d_in[0];
    float* out = (float*)d_out;
    // 8 batches * 64 block-rows * 64 rows-per-block = 32768 dense rows.
    dim3 grid(8 * 64 * 64);
    dim3 block(256);
    bs_softmax_kernel<<<grid, block, 0, stream>>>(x, out);
}